// Round 1
// baseline (9563.338 us; speedup 1.0000x reference)
//
#include <hip/hip_runtime.h>

#define B_ 8
#define N_ 512
#define PD_ 512
#define E_ 768
#define H_ 12
#define DEPTH_ 8
#define FF_ 3072
#define HD_ 64
#define M_ (B_*N_)   // 4096 rows
#define EPS_ 1e-5f

// ---------------------------------------------------------------------------
// Generic NT GEMM: C[M,Nt] = A[M,K] @ Bw[Nt,K]^T + bias (+pos) (relu)
// A row-major (lda=K), Bw row-major [out,in] (ldb=K)  -> both k-contiguous.
// Tile 64x64, BK=16, 256 threads, 4x4 per thread, float4 LDS reads.
// Assumes M%64==0, Nt%64==0, K%16==0 (true for all shapes here).
// ---------------------------------------------------------------------------
__global__ __launch_bounds__(256) void gemm_nt(
    const float* __restrict__ A, const float* __restrict__ Bw,
    const float* __restrict__ bias, const float* __restrict__ pos,
    float* __restrict__ C, int Nt, int K, int relu)
{
  __shared__ float As[16][68];   // k-major, +4 pad keeps float4 alignment
  __shared__ float Bs[16][68];
  const int t  = threadIdx.x;
  const int tx = t & 15, ty = t >> 4;
  const int lr = t >> 2, lk = (t & 3) << 2;
  const int bm = blockIdx.y, bn = blockIdx.x;
  const float* Ap = A  + (size_t)(bm * 64 + lr) * K + lk;
  const float* Bp = Bw + (size_t)(bn * 64 + lr) * K + lk;
  float acc[4][4] = {};
  for (int k0 = 0; k0 < K; k0 += 16) {
    float4 av = *(const float4*)(Ap + k0);
    float4 bv = *(const float4*)(Bp + k0);
    As[lk+0][lr] = av.x; As[lk+1][lr] = av.y; As[lk+2][lr] = av.z; As[lk+3][lr] = av.w;
    Bs[lk+0][lr] = bv.x; Bs[lk+1][lr] = bv.y; Bs[lk+2][lr] = bv.z; Bs[lk+3][lr] = bv.w;
    __syncthreads();
#pragma unroll
    for (int kk = 0; kk < 16; ++kk) {
      float4 a = *(const float4*)&As[kk][ty << 2];
      float4 b = *(const float4*)&Bs[kk][tx << 2];
      acc[0][0] += a.x*b.x; acc[0][1] += a.x*b.y; acc[0][2] += a.x*b.z; acc[0][3] += a.x*b.w;
      acc[1][0] += a.y*b.x; acc[1][1] += a.y*b.y; acc[1][2] += a.y*b.z; acc[1][3] += a.y*b.w;
      acc[2][0] += a.z*b.x; acc[2][1] += a.z*b.y; acc[2][2] += a.z*b.z; acc[2][3] += a.z*b.w;
      acc[3][0] += a.w*b.x; acc[3][1] += a.w*b.y; acc[3][2] += a.w*b.z; acc[3][3] += a.w*b.w;
    }
    __syncthreads();
  }
  const int gn = bn * 64 + (tx << 2);
  const float4 bias4 = *(const float4*)(bias + gn);
#pragma unroll
  for (int i = 0; i < 4; ++i) {
    const int gm = bm * 64 + (ty << 2) + i;
    float4 r;
    r.x = acc[i][0] + bias4.x; r.y = acc[i][1] + bias4.y;
    r.z = acc[i][2] + bias4.z; r.w = acc[i][3] + bias4.w;
    if (pos) {  // patch-embed epilogue: += pos[row % N][col]  (Nt==E_ here)
      const float4 p = *(const float4*)(pos + (size_t)(gm & (N_ - 1)) * E_ + gn);
      r.x += p.x; r.y += p.y; r.z += p.z; r.w += p.w;
    }
    if (relu) {
      r.x = fmaxf(r.x, 0.f); r.y = fmaxf(r.y, 0.f);
      r.z = fmaxf(r.z, 0.f); r.w = fmaxf(r.w, 0.f);
    }
    *(float4*)(C + (size_t)gm * Nt + gn) = r;
  }
}

// ---------------------------------------------------------------------------
// scores[b,h,i,j] = (q_i . k_j) / 8   (pre-softmax), written to d_out attn slab
// q[i,d] = qkv[b, i, h*64+d]          (row stride 3E)
// k[j,d] = qkv[b, j, E + h*64+d]
// Per (b,h): 512x512, K=64. Tile 64x64.
// ---------------------------------------------------------------------------
__global__ __launch_bounds__(256) void scores_gemm(
    const float* __restrict__ qkv, float* __restrict__ attn)
{
  __shared__ float As[16][68];
  __shared__ float Bs[16][68];
  const int t  = threadIdx.x;
  const int tx = t & 15, ty = t >> 4;
  const int lr = t >> 2, lk = (t & 3) << 2;
  const int bh = blockIdx.z;
  const int b  = bh / H_, h = bh % H_;
  const int bi = blockIdx.y, bj = blockIdx.x;
  const float* qp = qkv + (size_t)b * N_ * 3 * E_ + (size_t)(bi * 64 + lr) * 3 * E_ + h * HD_ + lk;
  const float* kp = qkv + (size_t)b * N_ * 3 * E_ + (size_t)(bj * 64 + lr) * 3 * E_ + E_ + h * HD_ + lk;
  float acc[4][4] = {};
  for (int k0 = 0; k0 < HD_; k0 += 16) {
    float4 av = *(const float4*)(qp + k0);
    float4 bv = *(const float4*)(kp + k0);
    As[lk+0][lr] = av.x; As[lk+1][lr] = av.y; As[lk+2][lr] = av.z; As[lk+3][lr] = av.w;
    Bs[lk+0][lr] = bv.x; Bs[lk+1][lr] = bv.y; Bs[lk+2][lr] = bv.z; Bs[lk+3][lr] = bv.w;
    __syncthreads();
#pragma unroll
    for (int kk = 0; kk < 16; ++kk) {
      float4 a = *(const float4*)&As[kk][ty << 2];
      float4 b4 = *(const float4*)&Bs[kk][tx << 2];
      acc[0][0] += a.x*b4.x; acc[0][1] += a.x*b4.y; acc[0][2] += a.x*b4.z; acc[0][3] += a.x*b4.w;
      acc[1][0] += a.y*b4.x; acc[1][1] += a.y*b4.y; acc[1][2] += a.y*b4.z; acc[1][3] += a.y*b4.w;
      acc[2][0] += a.z*b4.x; acc[2][1] += a.z*b4.y; acc[2][2] += a.z*b4.z; acc[2][3] += a.z*b4.w;
      acc[3][0] += a.w*b4.x; acc[3][1] += a.w*b4.y; acc[3][2] += a.w*b4.z; acc[3][3] += a.w*b4.w;
    }
    __syncthreads();
  }
  float* out = attn + (size_t)bh * N_ * N_;
  const int gj = bj * 64 + (tx << 2);
#pragma unroll
  for (int i = 0; i < 4; ++i) {
    const int gi = bi * 64 + (ty << 2) + i;
    float4 r = { acc[i][0]*0.125f, acc[i][1]*0.125f, acc[i][2]*0.125f, acc[i][3]*0.125f };
    *(float4*)(out + (size_t)gi * N_ + gj) = r;
  }
}

// ---------------------------------------------------------------------------
// in-place row softmax over 512 elements; one block (256 thr) per row
// ---------------------------------------------------------------------------
__global__ __launch_bounds__(256) void softmax_rows(float* __restrict__ attn)
{
  float* r = attn + (size_t)blockIdx.x * N_;
  const int t = threadIdx.x;
  float2 v = *(float2*)(r + t * 2);
  float m = fmaxf(v.x, v.y);
#pragma unroll
  for (int o = 32; o > 0; o >>= 1) m = fmaxf(m, __shfl_down(m, o));
  __shared__ float red[8];
  const int wave = t >> 6, lane = t & 63;
  if (lane == 0) red[wave] = m;
  __syncthreads();
  m = fmaxf(fmaxf(red[0], red[1]), fmaxf(red[2], red[3]));
  const float e0 = __expf(v.x - m), e1 = __expf(v.y - m);
  float s = e0 + e1;
#pragma unroll
  for (int o = 32; o > 0; o >>= 1) s += __shfl_down(s, o);
  if (lane == 0) red[4 + wave] = s;
  __syncthreads();
  const float inv = 1.0f / (red[4] + red[5] + red[6] + red[7]);
  float2 w = { e0 * inv, e1 * inv };
  *(float2*)(r + t * 2) = w;
}

// ---------------------------------------------------------------------------
// o[b, i, h*64+d] = sum_j attn[b,h,i,j] * v[b,j,h*64+d]
// Per (b,h): M=512, Nt=64, K=512.  A is NT-style (j contiguous), B is NN.
// ---------------------------------------------------------------------------
__global__ __launch_bounds__(256) void attnv_gemm(
    const float* __restrict__ attn, const float* __restrict__ qkv,
    float* __restrict__ o)
{
  __shared__ float As[16][68];
  __shared__ float Bs[16][68];
  const int t  = threadIdx.x;
  const int tx = t & 15, ty = t >> 4;
  const int lr = t >> 2, lk = (t & 3) << 2;   // A staging
  const int jj = t >> 4, dd = (t & 15) << 2;  // B staging
  const int bh = blockIdx.z;
  const int b  = bh / H_, h = bh % H_;
  const int bi = blockIdx.y;
  const float* ap = attn + (size_t)bh * N_ * N_ + (size_t)(bi * 64 + lr) * N_ + lk;
  const float* vp = qkv + (size_t)b * N_ * 3 * E_ + 2 * E_ + h * HD_;
  float acc[4][4] = {};
  for (int k0 = 0; k0 < N_; k0 += 16) {
    float4 av = *(const float4*)(ap + k0);
    float4 bv = *(const float4*)(vp + (size_t)(k0 + jj) * 3 * E_ + dd);
    As[lk+0][lr] = av.x; As[lk+1][lr] = av.y; As[lk+2][lr] = av.z; As[lk+3][lr] = av.w;
    *(float4*)&Bs[jj][dd] = bv;
    __syncthreads();
#pragma unroll
    for (int kk = 0; kk < 16; ++kk) {
      float4 a = *(const float4*)&As[kk][ty << 2];
      float4 b4 = *(const float4*)&Bs[kk][tx << 2];
      acc[0][0] += a.x*b4.x; acc[0][1] += a.x*b4.y; acc[0][2] += a.x*b4.z; acc[0][3] += a.x*b4.w;
      acc[1][0] += a.y*b4.x; acc[1][1] += a.y*b4.y; acc[1][2] += a.y*b4.z; acc[1][3] += a.y*b4.w;
      acc[2][0] += a.z*b4.x; acc[2][1] += a.z*b4.y; acc[2][2] += a.z*b4.z; acc[2][3] += a.z*b4.w;
      acc[3][0] += a.w*b4.x; acc[3][1] += a.w*b4.y; acc[3][2] += a.w*b4.z; acc[3][3] += a.w*b4.w;
    }
    __syncthreads();
  }
  const int gd = h * HD_ + (tx << 2);
#pragma unroll
  for (int i = 0; i < 4; ++i) {
    const int gi = b * N_ + bi * 64 + (ty << 2) + i;
    float4 r = { acc[i][0], acc[i][1], acc[i][2], acc[i][3] };
    *(float4*)(o + (size_t)gi * E_ + gd) = r;
  }
}

// ---------------------------------------------------------------------------
// x = LayerNorm(x + y) * scale + bias, row length 768; one block per row
// ---------------------------------------------------------------------------
__global__ __launch_bounds__(256) void ln_residual(
    float* __restrict__ x, const float* __restrict__ y,
    const float* __restrict__ sc, const float* __restrict__ bi)
{
  const size_t row = blockIdx.x;
  float* xr = x + row * E_;
  const float* yr = y + row * E_;
  const int t = threadIdx.x;
  const float v0 = xr[t]       + yr[t];
  const float v1 = xr[t + 256] + yr[t + 256];
  const float v2 = xr[t + 512] + yr[t + 512];
  float s = v0 + v1 + v2;
  float q = v0*v0 + v1*v1 + v2*v2;
#pragma unroll
  for (int o = 32; o > 0; o >>= 1) { s += __shfl_down(s, o); q += __shfl_down(q, o); }
  __shared__ float red[8];
  const int wave = t >> 6, lane = t & 63;
  if (lane == 0) { red[wave] = s; red[4 + wave] = q; }
  __syncthreads();
  s = red[0] + red[1] + red[2] + red[3];
  q = red[4] + red[5] + red[6] + red[7];
  const float mean = s * (1.0f / E_);
  const float var  = q * (1.0f / E_) - mean * mean;
  const float rstd = rsqrtf(var + EPS_);
  xr[t]       = (v0 - mean) * rstd * sc[t]       + bi[t];
  xr[t + 256] = (v1 - mean) * rstd * sc[t + 256] + bi[t + 256];
  xr[t + 512] = (v2 - mean) * rstd * sc[t + 512] + bi[t + 512];
}

// ---------------------------------------------------------------------------
// pooled[b,e] = mean over n of x[b,n,e]
// ---------------------------------------------------------------------------
__global__ __launch_bounds__(256) void mean_pool(
    const float* __restrict__ x, float* __restrict__ out)
{
  const int idx = blockIdx.x * 256 + threadIdx.x;  // 0..6143
  const int b = idx / E_, e = idx % E_;
  const float* p = x + (size_t)b * N_ * E_ + e;
  float s = 0.f;
  for (int n = 0; n < N_; ++n) s += p[(size_t)n * E_];
  out[idx] = s * (1.0f / N_);
}

extern "C" void kernel_launch(void* const* d_in, const int* in_sizes, int n_in,
                              void* d_out, int out_size, void* d_ws, size_t ws_size,
                              hipStream_t stream)
{
  const float* patches = (const float*)d_in[0];
  const float* Wp    = (const float*)d_in[1];
  const float* bp    = (const float*)d_in[2];
  const float* pos   = (const float*)d_in[3];
  const float* qkv_w = (const float*)d_in[4];
  const float* qkv_b = (const float*)d_in[5];
  const float* out_w = (const float*)d_in[6];
  const float* out_b = (const float*)d_in[7];
  const float* ln1s  = (const float*)d_in[8];
  const float* ln1b  = (const float*)d_in[9];
  const float* w1    = (const float*)d_in[10];
  const float* b1    = (const float*)d_in[11];
  const float* w2    = (const float*)d_in[12];
  const float* b2    = (const float*)d_in[13];
  const float* ln2s  = (const float*)d_in[14];
  const float* ln2b  = (const float*)d_in[15];

  float* pooled = (float*)d_out;
  float* attns  = pooled + (size_t)B_ * E_;   // [DEPTH,B,H,N,N]

  // workspace layout (~108 MB)
  float* x    = (float*)d_ws;                 // [M,E]
  float* qkv  = x    + (size_t)M_ * E_;       // [M,3E]
  float* buf1 = qkv  + (size_t)M_ * 3 * E_;   // [M,FF]  (also o_tmp [M,E])
  float* buf2 = buf1 + (size_t)M_ * FF_;      // [M,E]

  const dim3 blk(256);

  // patch embed: x = patches @ Wp^T + bp + pos
  gemm_nt<<<dim3(E_ / 64, M_ / 64), blk, 0, stream>>>(
      patches, Wp, bp, pos, x, E_, PD_, 0);

  for (int L = 0; L < DEPTH_; ++L) {
    float* attnL = attns + (size_t)L * B_ * H_ * N_ * N_;
    // qkv = x @ qkv_w^T + qkv_b
    gemm_nt<<<dim3(3 * E_ / 64, M_ / 64), blk, 0, stream>>>(
        x, qkv_w + (size_t)L * 3 * E_ * E_, qkv_b + (size_t)L * 3 * E_,
        nullptr, qkv, 3 * E_, E_, 0);
    // scores (pre-softmax, scaled) -> attn slab
    scores_gemm<<<dim3(N_ / 64, N_ / 64, B_ * H_), blk, 0, stream>>>(qkv, attnL);
    // softmax in place
    softmax_rows<<<dim3(B_ * H_ * N_), blk, 0, stream>>>(attnL);
    // o_tmp = attn @ v   -> buf1 [M,E]
    attnv_gemm<<<dim3(1, N_ / 64, B_ * H_), blk, 0, stream>>>(attnL, qkv, buf1);
    // o2 = o_tmp @ out_w^T + out_b -> buf2
    gemm_nt<<<dim3(E_ / 64, M_ / 64), blk, 0, stream>>>(
        buf1, out_w + (size_t)L * E_ * E_, out_b + (size_t)L * E_,
        nullptr, buf2, E_, E_, 0);
    // x = LN(x + o2)
    ln_residual<<<dim3(M_), blk, 0, stream>>>(
        x, buf2, ln1s + (size_t)L * E_, ln1b + (size_t)L * E_);
    // h1 = relu(x @ w1^T + b1) -> buf1 [M,FF]
    gemm_nt<<<dim3(FF_ / 64, M_ / 64), blk, 0, stream>>>(
        x, w1 + (size_t)L * FF_ * E_, b1 + (size_t)L * FF_,
        nullptr, buf1, FF_, E_, 1);
    // ff2 = h1 @ w2^T + b2 -> buf2
    gemm_nt<<<dim3(E_ / 64, M_ / 64), blk, 0, stream>>>(
        buf1, w2 + (size_t)L * E_ * FF_, b2 + (size_t)L * E_,
        nullptr, buf2, E_, FF_, 0);
    // x = LN(x + ff2)
    ln_residual<<<dim3(M_), blk, 0, stream>>>(
        x, buf2, ln2s + (size_t)L * E_, ln2b + (size_t)L * E_);
  }

  // pooled = mean over n
  mean_pool<<<dim3((B_ * E_) / 256), blk, 0, stream>>>(x, pooled);
}